// Round 2
// baseline (3504.938 us; speedup 1.0000x reference)
//
#include <hip/hip_runtime.h>
#include <math.h>

// Model dims (fixed by the reference)
#define T_DIM 512
#define B_DIM 64
#define J_DIM 256
#define H_DIM 256
#define K_TAP 25
#define NL    3
#define M_DIM (T_DIM*B_DIM)   // 32768 rows = (t,b)
#define NBH   (B_DIM*H_DIM)   // 16384
#define STATB 128             // partial-reduction blocks for BN stats

// ---------------------------------------------------------------------------
// 1) DCLS gaussian kernel, delay-major: kd[d][j][o] = W[o,j]*gnorm[o,j,24-d]
// ---------------------------------------------------------------------------
__global__ void build_kern_k(const float* __restrict__ W, const float* __restrict__ P,
                             float* __restrict__ kd, int layer){
  const int j = blockIdx.x;     // 0..255
  const int o = threadIdx.x;    // 0..255
  const float w = W[(layer*H_DIM + o)*J_DIM + j];
  const float p = P[(layer*H_DIM + o)*J_DIM + j];
  const float c = p + 12.0f;              // P + K//2
  const float s = 0.77f;                  // |0.5| + 0.27
  float g[K_TAP];
  float ssum = 0.f;
#pragma unroll
  for(int k=0;k<K_TAP;k++){
    float z = ((float)k - c) / s;
    g[k] = expf(-0.5f*z*z);
    ssum += g[k];
  }
  const float inv = 1.0f/(ssum + 1e-7f);
#pragma unroll
  for(int k=0;k<K_TAP;k++){
    const int d = (K_TAP-1) - k;
    kd[(d*J_DIM + j)*H_DIM + o] = w * (g[k] * inv);
  }
}

// ---------------------------------------------------------------------------
// 2) Causal delayed conv as tiled GEMM (fp32 SIMT).
//    y[r,o] = sum_d sum_j x[r-64d, j] * kd[d][j][o], x row<0 -> 0.
//    Input x is either f32 (layer 0) or u8 spikes (layers 1,2).
// ---------------------------------------------------------------------------
#define BM 128
#define BN 128
#define BK 16

__device__ __forceinline__ float4 load4(const float* p){ return *(const float4*)p; }
__device__ __forceinline__ float4 load4(const unsigned char* p){
  uchar4 v = *(const uchar4*)p;
  return make_float4((float)v.x, (float)v.y, (float)v.z, (float)v.w);
}

template<typename TIN>
__global__ __launch_bounds__(256) void conv_gemm_k(const TIN* __restrict__ x,
                                                   const float* __restrict__ kd,
                                                   float* __restrict__ y){
  __shared__ float As[BK][BM+4];   // A transposed: As[k][m]
  __shared__ float Bs[BK][BN+4];   // Bs[k][n]
  const int tid = threadIdx.x;
  const int m0 = blockIdx.x * BM;
  const int n0 = blockIdx.y * BN;
  const int tx = tid & 15;
  const int ty = tid >> 4;
  const int ar = tid >> 2;         // 0..63 (+64 second half)
  const int ac = (tid & 3) << 2;   // 0,4,8,12
  const int br = tid >> 5;         // 0..7 (+8)
  const int bc = (tid & 31) << 2;  // 0..124

  float acc[8][8];
#pragma unroll
  for(int i=0;i<8;i++)
#pragma unroll
    for(int j=0;j<8;j++) acc[i][j] = 0.f;

  for(int d=0; d<K_TAP; ++d){
    const int shift = d * B_DIM;
    const int r0 = m0 + ar - shift;
    const int r1 = m0 + 64 + ar - shift;
    const bool ok0 = (r0 >= 0);
    const bool ok1 = (r1 >= 0);
    for(int jc=0; jc<J_DIM; jc+=BK){
      float4 a0 = {0.f,0.f,0.f,0.f}, a1 = {0.f,0.f,0.f,0.f};
      if(ok0) a0 = load4(x + r0*J_DIM + jc + ac);
      if(ok1) a1 = load4(x + r1*J_DIM + jc + ac);
      const float4 b0 = *(const float4*)(kd + (d*J_DIM + jc + br    )*H_DIM + n0 + bc);
      const float4 b1 = *(const float4*)(kd + (d*J_DIM + jc + 8 + br)*H_DIM + n0 + bc);
      __syncthreads();                       // protect prior iteration's LDS reads
      As[ac+0][ar]    = a0.x; As[ac+1][ar]    = a0.y; As[ac+2][ar]    = a0.z; As[ac+3][ar]    = a0.w;
      As[ac+0][64+ar] = a1.x; As[ac+1][64+ar] = a1.y; As[ac+2][64+ar] = a1.z; As[ac+3][64+ar] = a1.w;
      *(float4*)&Bs[br  ][bc] = b0;
      *(float4*)&Bs[br+8][bc] = b1;
      __syncthreads();
#pragma unroll
      for(int k=0;k<BK;k++){
        const float4 av0 = *(const float4*)&As[k][ty*8];
        const float4 av1 = *(const float4*)&As[k][ty*8+4];
        const float4 bv0 = *(const float4*)&Bs[k][tx*4];
        const float4 bv1 = *(const float4*)&Bs[k][64 + tx*4];
        const float a[8] = {av0.x,av0.y,av0.z,av0.w, av1.x,av1.y,av1.z,av1.w};
        const float b[8] = {bv0.x,bv0.y,bv0.z,bv0.w, bv1.x,bv1.y,bv1.z,bv1.w};
#pragma unroll
        for(int i=0;i<8;i++)
#pragma unroll
          for(int j=0;j<8;j++)
            acc[i][j] = fmaf(a[i], b[j], acc[i][j]);
      }
    }
  }
#pragma unroll
  for(int i=0;i<8;i++){
    const int row = m0 + ty*8 + i;
    float4 c0 = {acc[i][0],acc[i][1],acc[i][2],acc[i][3]};
    float4 c1 = {acc[i][4],acc[i][5],acc[i][6],acc[i][7]};
    *(float4*)(y + row*H_DIM + n0 + tx*4)      = c0;
    *(float4*)(y + row*H_DIM + n0 + 64 + tx*4) = c1;
  }
}

// ---------------------------------------------------------------------------
// 3) BatchNorm training stats (two-stage, fp64 accumulators, fixed order)
// ---------------------------------------------------------------------------
__global__ void bn_stats_k(const float* __restrict__ y, double* __restrict__ part){
  const int o   = threadIdx.x;
  const int blk = blockIdx.x;         // 0..127
  const int rows = M_DIM / STATB;     // 256
  const float* p = y + (size_t)(blk*rows)*H_DIM + o;
  double s = 0.0, s2 = 0.0;
  for(int r=0;r<rows;r++){
    double v = (double)p[r*H_DIM];
    s  += v;
    s2 += v*v;
  }
  part[blk*H_DIM + o]               = s;
  part[STATB*H_DIM + blk*H_DIM + o] = s2;
}

__global__ void bn_final_k(const double* __restrict__ part, float* __restrict__ sc,
                           float* __restrict__ sh, const float* __restrict__ gamma_,
                           const float* __restrict__ bb_, int layer){
  const int o = threadIdx.x;
  double s = 0.0, s2 = 0.0;
  for(int b=0;b<STATB;b++){
    s  += part[b*H_DIM + o];
    s2 += part[STATB*H_DIM + b*H_DIM + o];
  }
  const double inv_n = 1.0 / (double)M_DIM;
  const double m   = s * inv_n;
  const double var = s2 * inv_n - m*m;      // biased, like jnp.var
  const double rs  = 1.0 / sqrt(var + (double)1e-5f);
  const float g  = gamma_[layer*H_DIM + o];
  const float bv = bb_[layer*H_DIM + o];
  const float scale = (float)((double)g * rs);
  sc[o] = scale;
  sh[o] = (float)((double)bv - m*(double)scale);
}

// ---------------------------------------------------------------------------
// 4) LIF soft-reset scan. One thread per (b,h), 8-deep prefetch.
//    TOUT=u8 for inter-layer spikes, f32 for final output (in-place on d_out).
//    NOTE: no __restrict__ — yin/sout alias for the final layer.
// ---------------------------------------------------------------------------
template<typename TOUT>
__global__ void lif_k(const float* yin, TOUT* sout,
                      const float* __restrict__ sc_, const float* __restrict__ sh_,
                      const float* __restrict__ beta_, const float* __restrict__ U0_,
                      int layer){
  const int idx = blockIdx.x*64 + threadIdx.x;   // 0..16383 = b*256+h
  const int h = idx & (H_DIM-1);
  const float scale = sc_[h];
  const float shift = sh_[h];
  const float beta  = beta_[layer*H_DIM + h];
  const float ombeta = 1.0f - beta;
  float U = U0_[layer*NBH + idx];
  float S = 0.f;
  float cur[8];
#pragma unroll
  for(int i=0;i<8;i++) cur[i] = yin[i*NBH + idx];
  for(int t=0;t<T_DIM;t+=8){
    float nx[8];
#pragma unroll
    for(int i=0;i<8;i++){
      const int tt = t + 8 + i;
      nx[i] = (tt < T_DIM) ? yin[tt*NBH + idx] : 0.f;
    }
#pragma unroll
    for(int i=0;i<8;i++){
      const float yv = fmaf(cur[i], scale, shift);
      U = beta*(U - S) + ombeta*yv;
      S = (U > 1.0f) ? 1.f : 0.f;              // (U - THETA) > 0
      sout[(t+i)*NBH + idx] = (TOUT)S;
    }
#pragma unroll
    for(int i=0;i<8;i++) cur[i] = nx[i];
  }
}

// ---------------------------------------------------------------------------
// Launch. ws layout (15.47 MB total — small to stay far inside ws_size):
//   kd   [0,          6,553,600)    25*256*256 f32 (GEMM B)
//   spk  [6,553,600, 14,942,208)    32768*256 u8 inter-layer spikes
//   part [14,942,208,15,466,496)    2*128*256 f64 BN partials
//   sc   [15,466,496,+1024) f32 ; sh [15,467,520,+1024) f32
// Every layer's conv output y lives in d_out (fully rewritten before any read).
// ---------------------------------------------------------------------------
extern "C" void kernel_launch(void* const* d_in, const int* in_sizes, int n_in,
                              void* d_out, int out_size, void* d_ws, size_t ws_size,
                              hipStream_t stream){
  const float* x    = (const float*)d_in[0];
  const float* W    = (const float*)d_in[1];
  const float* P    = (const float*)d_in[2];
  const float* beta = (const float*)d_in[3];
  const float* gam  = (const float*)d_in[4];
  const float* bb   = (const float*)d_in[5];
  const float* U0   = (const float*)d_in[6];
  float* out = (float*)d_out;

  char* ws = (char*)d_ws;
  float*         kd   = (float*)(ws);
  unsigned char* spk  = (unsigned char*)(ws + 6553600);
  double*        part = (double*)(ws + 14942208);
  float*         sc   = (float*)(ws + 15466496);
  float*         sh   = sc + 256;

  const dim3 cgrid(M_DIM/BM, H_DIM/BN), cblk(256);

  for(int l=0;l<NL;l++){
    build_kern_k<<<dim3(J_DIM), dim3(H_DIM), 0, stream>>>(W, P, kd, l);
    if(l==0) conv_gemm_k<float><<<cgrid, cblk, 0, stream>>>(x, kd, out);
    else     conv_gemm_k<unsigned char><<<cgrid, cblk, 0, stream>>>(spk, kd, out);
    bn_stats_k<<<dim3(STATB), dim3(H_DIM), 0, stream>>>(out, part);
    bn_final_k<<<dim3(1), dim3(H_DIM), 0, stream>>>(part, sc, sh, gam, bb, l);
    if(l < NL-1) lif_k<unsigned char><<<dim3(NBH/64), dim3(64), 0, stream>>>(out, spk, sc, sh, beta, U0, l);
    else         lif_k<float>        <<<dim3(NBH/64), dim3(64), 0, stream>>>(out, out, sc, sh, beta, U0, l);
  }
}

// Round 4
// 981.486 us; speedup vs baseline: 3.5711x; 3.5711x over previous
//
#include <hip/hip_runtime.h>
#include <math.h>

// Model dims (fixed by the reference)
#define T_DIM 512
#define B_DIM 64
#define J_DIM 256
#define H_DIM 256
#define K_TAP 25
#define NL    3
#define M_DIM (T_DIM*B_DIM)   // 32768 rows = (t,b)
#define NBH   (B_DIM*H_DIM)   // 16384
#define STATB 128

// conv GEMM tiling
#define MB 128
#define NB 128
#define KS 32
#define NST (K_TAP*(J_DIM/KS))  // 200 K-steps

typedef __attribute__((ext_vector_type(8))) short bf16x8;
typedef __attribute__((ext_vector_type(4))) float f32x4;

__device__ __forceinline__ unsigned short f2bf(float f){      // RNE f32->bf16
  unsigned u = __float_as_uint(f);
  return (unsigned short)((u + 0x7FFFu + ((u>>16)&1u)) >> 16);
}
__device__ __forceinline__ float bf2f(unsigned short h){
  return __uint_as_float(((unsigned)h)<<16);
}
__device__ __forceinline__ void gl16(const void* g, void* l){ // async global->LDS, 16B/lane
  __builtin_amdgcn_global_load_lds((const __attribute__((address_space(1))) unsigned int*)g,
                                   (__attribute__((address_space(3))) unsigned int*)l, 16, 0, 0);
}

// ---------------------------------------------------------------------------
// 0) cast f32 binary input -> u8 spikes
// ---------------------------------------------------------------------------
__global__ void cast_u8_k(const float* __restrict__ x, unsigned char* __restrict__ s){
  const int i = blockIdx.x*256 + threadIdx.x;       // one float4 per thread
  const float4 v = *(const float4*)(x + (size_t)i*4);
  uchar4 o; o.x=(unsigned char)v.x; o.y=(unsigned char)v.y;
  o.z=(unsigned char)v.z; o.w=(unsigned char)v.w;
  *(uchar4*)(s + (size_t)i*4) = o;
}

// ---------------------------------------------------------------------------
// 1) DCLS gaussian kernel -> 3-way bf16 split (hi+mid+lo == kd to 2^-24 rel),
//    layout [d][o][j] (j contiguous). kd[d][o][j] = W[o,j]*gnorm[o,j,k=24-d].
//    Each residual subtraction is exact in fp32 (Sterbenz), so
//    v - (hi+mid+lo) <= 2^-24 |v| : fp32-equivalent weights.
// ---------------------------------------------------------------------------
__global__ void build_kern_k(const float* __restrict__ W, const float* __restrict__ P,
                             unsigned short* __restrict__ kdh, unsigned short* __restrict__ kdm,
                             unsigned short* __restrict__ kdl, int layer){
  const int o = blockIdx.x, j = threadIdx.x;
  const float w = W[(layer*H_DIM + o)*J_DIM + j];
  const float p = P[(layer*H_DIM + o)*J_DIM + j];
  const float c = p + 12.0f;              // P + K//2
  const float s = 0.77f;                  // |0.5| + 0.27
  float g[K_TAP]; float ssum = 0.f;
#pragma unroll
  for(int k=0;k<K_TAP;k++){ float z = ((float)k - c)/s; g[k] = expf(-0.5f*z*z); ssum += g[k]; }
  const float inv = 1.0f/(ssum + 1e-7f);
#pragma unroll
  for(int k=0;k<K_TAP;k++){
    const int d = (K_TAP-1)-k;
    const float v  = w * (g[k]*inv);
    const unsigned short h1 = f2bf(v);
    const float r1 = v - bf2f(h1);
    const unsigned short h2 = f2bf(r1);
    const float r2 = r1 - bf2f(h2);
    const unsigned short h3 = f2bf(r2);
    const size_t idx = (size_t)(d*H_DIM + o)*J_DIM + j;
    kdh[idx] = h1; kdm[idx] = h2; kdl[idx] = h3;
  }
}

// ---------------------------------------------------------------------------
// 2) Delayed causal conv as MFMA GEMM.
//    y[r,o] = sum_d sum_j spk[r-64d, j]*(hi+mid+lo)[d,o,j], rows<0 -> 0.
//    128x128 tile, 4 waves (2x2), 16x16x32 bf16 MFMA, double-buffered LDS.
//    A: u8 spikes reg-staged (bit-expand to bf16), B: global_load_lds x16B.
// ---------------------------------------------------------------------------
__global__ __launch_bounds__(256,2) void conv_mfma_k(const unsigned char* __restrict__ spk,
    const unsigned short* __restrict__ kdh, const unsigned short* __restrict__ kdm,
    const unsigned short* __restrict__ kdl, float* __restrict__ y){
  __shared__ unsigned short lds[2][4*4096];   // per buf: A | H | M | L, each [128][32]
  const int tid = threadIdx.x, lane = tid & 63, wave = tid >> 6;
  const int m0 = blockIdx.x * MB, n0 = blockIdx.y * NB;
  const int wm0 = (wave >> 1) << 6, wn0 = (wave & 1) << 6;

  const int arow = tid >> 1;          // A staging: row 0..127
  const int acol = (tid & 1) << 4;    // u8 col offset 0/16
  const int brow = tid >> 2;          // B staging: row 0..63 within 64-row group
  const int boff = (tid & 3) << 3;    // elem offset 0,8,16,24

  f32x4 acc[4][4];
#pragma unroll
  for(int m=0;m<4;m++)
#pragma unroll
    for(int n=0;n<4;n++) acc[m][n] = (f32x4){0.f,0.f,0.f,0.f};

  unsigned areg[4];

#define LOAD_A(t) do{ \
    const int d_ = (t)>>3, jc_ = ((t)&7)<<5; \
    const int gr_ = m0 + arow - (d_<<6); \
    if(gr_ >= 0){ \
      const uint4 v_ = *(const uint4*)(spk + (size_t)gr_*J_DIM + jc_ + acol); \
      areg[0]=v_.x; areg[1]=v_.y; areg[2]=v_.z; areg[3]=v_.w; \
    } else { areg[0]=0u; areg[1]=0u; areg[2]=0u; areg[3]=0u; } \
  }while(0)

#define STAGE_B(buf,t) do{ \
    const int d_ = (t)>>3, jc_ = ((t)&7)<<5; \
    const size_t go_ = (size_t)(d_*H_DIM + n0 + brow)*J_DIM + jc_ + boff; \
    unsigned short* l0_ = &lds[buf][4096]  + wave*512; \
    unsigned short* l1_ = &lds[buf][8192]  + wave*512; \
    unsigned short* l2_ = &lds[buf][12288] + wave*512; \
    gl16(kdh + go_,            l0_); \
    gl16(kdh + go_ + 64*J_DIM, l0_ + 2048); \
    gl16(kdm + go_,            l1_); \
    gl16(kdm + go_ + 64*J_DIM, l1_ + 2048); \
    gl16(kdl + go_,            l2_); \
    gl16(kdl + go_ + 64*J_DIM, l2_ + 2048); \
  }while(0)

#define WRITE_A(buf) do{ \
    unsigned o_[8]; \
    _Pragma("unroll") \
    for(int q=0;q<4;q++){ \
      const unsigned w_ = areg[q]; \
      o_[2*q]   = ((w_ & 1u)         | ((w_ & 0x100u)      << 8)) * 0x3F80u; \
      o_[2*q+1] = (((w_ >> 16) & 1u) | ((w_ & 0x1000000u) >> 8)) * 0x3F80u; \
    } \
    unsigned* dst_ = (unsigned*)&lds[buf][0] + arow*16 + ((tid&1)<<3); \
    *(uint4*)dst_     = (uint4){o_[0],o_[1],o_[2],o_[3]}; \
    *(uint4*)(dst_+4) = (uint4){o_[4],o_[5],o_[6],o_[7]}; \
  }while(0)

  // prologue: stage step 0 into buf 0
  LOAD_A(0);
  STAGE_B(0,0);
  WRITE_A(0);
  __syncthreads();

  int cur = 0;
  for(int t=0; t<NST; ++t){
    const int nxt = cur ^ 1;
    if(t+1 < NST){ LOAD_A(t+1); STAGE_B(nxt, t+1); }   // issue early (T14)
    const unsigned short* A  = &lds[cur][0];
    const unsigned short* Hh = &lds[cur][4096];
    const unsigned short* Mm = &lds[cur][8192];
    const unsigned short* Ll = &lds[cur][12288];
    bf16x8 af[4], hf[4], mf[4], lf[4];
#pragma unroll
    for(int m=0;m<4;m++)
      af[m] = *(const bf16x8*)(A + (wm0 + m*16 + (lane&15))*KS + ((lane>>4)<<3));
#pragma unroll
    for(int n=0;n<4;n++){
      const int ro = (wn0 + n*16 + (lane&15))*KS + ((lane>>4)<<3);
      hf[n] = *(const bf16x8*)(Hh + ro);
      mf[n] = *(const bf16x8*)(Mm + ro);
      lf[n] = *(const bf16x8*)(Ll + ro);
    }
#pragma unroll
    for(int m=0;m<4;m++)
#pragma unroll
      for(int n=0;n<4;n++){
        acc[m][n] = __builtin_amdgcn_mfma_f32_16x16x32_bf16(af[m], hf[n], acc[m][n], 0,0,0);
        acc[m][n] = __builtin_amdgcn_mfma_f32_16x16x32_bf16(af[m], mf[n], acc[m][n], 0,0,0);
        acc[m][n] = __builtin_amdgcn_mfma_f32_16x16x32_bf16(af[m], lf[n], acc[m][n], 0,0,0);
      }
    if(t+1 < NST) WRITE_A(nxt);   // write-late: areg arrived under the MFMAs
    __syncthreads();
    cur = nxt;
  }

  // epilogue: C/D mapping col=lane&15, row=(lane>>4)*4+r  [m89-verified]
  const int r0 = m0 + wm0 + ((lane>>4)<<2);
  const int c0 = n0 + wn0 + (lane&15);
#pragma unroll
  for(int m=0;m<4;m++)
#pragma unroll
    for(int n=0;n<4;n++)
#pragma unroll
      for(int r=0;r<4;r++)
        y[(size_t)(r0 + m*16 + r)*H_DIM + c0 + n*16] = acc[m][n][r];
#undef LOAD_A
#undef STAGE_B
#undef WRITE_A
}

// ---------------------------------------------------------------------------
// 3) BatchNorm training stats (two-stage, fp64 accumulators, fixed order)
// ---------------------------------------------------------------------------
__global__ void bn_stats_k(const float* __restrict__ y, double* __restrict__ part){
  const int o   = threadIdx.x;
  const int blk = blockIdx.x;         // 0..127
  const int rows = M_DIM / STATB;     // 256
  const float* p = y + (size_t)(blk*rows)*H_DIM + o;
  double s = 0.0, s2 = 0.0;
  for(int r=0;r<rows;r++){
    double v = (double)p[(size_t)r*H_DIM];
    s  += v;
    s2 += v*v;
  }
  part[blk*H_DIM + o]               = s;
  part[STATB*H_DIM + blk*H_DIM + o] = s2;
}

__global__ void bn_final_k(const double* __restrict__ part, float* __restrict__ sc,
                           float* __restrict__ sh, const float* __restrict__ gamma_,
                           const float* __restrict__ bb_, int layer){
  const int o = threadIdx.x;
  double s = 0.0, s2 = 0.0;
  for(int b=0;b<STATB;b++){
    s  += part[b*H_DIM + o];
    s2 += part[STATB*H_DIM + b*H_DIM + o];
  }
  const double inv_n = 1.0 / (double)M_DIM;
  const double m   = s * inv_n;
  const double var = s2 * inv_n - m*m;      // biased, like jnp.var
  const double rs  = 1.0 / sqrt(var + (double)1e-5f);
  const float g  = gamma_[layer*H_DIM + o];
  const float bv = bb_[layer*H_DIM + o];
  const float scale = (float)((double)g * rs);
  sc[o] = scale;
  sh[o] = (float)((double)bv - m*(double)scale);
}

// ---------------------------------------------------------------------------
// 4) LIF soft-reset scan. One thread per (b,h), 8-deep prefetch.
//    TOUT=u8 inter-layer spikes, f32 final output (in-place on d_out).
//    NOTE: no __restrict__ on yin/sout — they alias for the final layer.
// ---------------------------------------------------------------------------
template<typename TOUT>
__global__ void lif_k(const float* yin, TOUT* sout,
                      const float* __restrict__ sc_, const float* __restrict__ sh_,
                      const float* __restrict__ beta_, const float* __restrict__ U0_,
                      int layer){
  const int idx = blockIdx.x*64 + threadIdx.x;   // 0..16383 = b*256+h
  const int h = idx & (H_DIM-1);
  const float scale = sc_[h];
  const float shift = sh_[h];
  const float beta  = beta_[layer*H_DIM + h];
  const float ombeta = 1.0f - beta;
  float U = U0_[layer*NBH + idx];
  float S = 0.f;
  float cur[8];
#pragma unroll
  for(int i=0;i<8;i++) cur[i] = yin[(size_t)i*NBH + idx];
  for(int t=0;t<T_DIM;t+=8){
    float nx[8];
#pragma unroll
    for(int i=0;i<8;i++){
      const int tt = t + 8 + i;
      nx[i] = (tt < T_DIM) ? yin[(size_t)tt*NBH + idx] : 0.f;
    }
#pragma unroll
    for(int i=0;i<8;i++){
      const float yv = fmaf(cur[i], scale, shift);
      U = beta*(U - S) + ombeta*yv;
      S = (U > 1.0f) ? 1.f : 0.f;              // (U - THETA) > 0
      sout[(size_t)(t+i)*NBH + idx] = (TOUT)S;
    }
#pragma unroll
    for(int i=0;i<8;i++) cur[i] = nx[i];
  }
}

// ---------------------------------------------------------------------------
// Launch. ws layout (18.75 MB total; < 33.5 MB d_out, < round-1's bad 40.6):
//   spk  [0,          8,388,608)    32768*256 u8 spikes (layer input)
//   kdh  [8,388,608, 11,665,408)    25*256*256 bf16 (hi)
//   kdm  [11,665,408,14,942,208)    25*256*256 bf16 (mid)
//   kdl  [14,942,208,18,219,008)    25*256*256 bf16 (lo)
//   part [18,219,008,18,743,296)    2*128*256 f64 BN partials
//   sc   [18,743,296,+1024) f32 ; sh [18,744,320,+1024) f32
// Conv y always lands in d_out (fully rewritten each layer before any read).
// ---------------------------------------------------------------------------
extern "C" void kernel_launch(void* const* d_in, const int* in_sizes, int n_in,
                              void* d_out, int out_size, void* d_ws, size_t ws_size,
                              hipStream_t stream){
  const float* x    = (const float*)d_in[0];
  const float* W    = (const float*)d_in[1];
  const float* P    = (const float*)d_in[2];
  const float* beta = (const float*)d_in[3];
  const float* gam  = (const float*)d_in[4];
  const float* bb   = (const float*)d_in[5];
  const float* U0   = (const float*)d_in[6];
  float* out = (float*)d_out;

  char* ws = (char*)d_ws;
  unsigned char*  spk  = (unsigned char*)ws;
  unsigned short* kdh  = (unsigned short*)(ws + 8388608);
  unsigned short* kdm  = (unsigned short*)(ws + 11665408);
  unsigned short* kdl  = (unsigned short*)(ws + 14942208);
  double*         part = (double*)(ws + 18219008);
  float*          sc   = (float*)(ws + 18743296);
  float*          sh   = sc + 256;

  cast_u8_k<<<dim3((M_DIM*J_DIM)/1024), dim3(256), 0, stream>>>(x, spk);

  for(int l=0;l<NL;l++){
    build_kern_k<<<dim3(H_DIM), dim3(J_DIM), 0, stream>>>(W, P, kdh, kdm, kdl, l);
    conv_mfma_k<<<dim3(M_DIM/MB, H_DIM/NB), dim3(256), 0, stream>>>(spk, kdh, kdm, kdl, out);
    bn_stats_k<<<dim3(STATB), dim3(H_DIM), 0, stream>>>(out, part);
    bn_final_k<<<dim3(1), dim3(H_DIM), 0, stream>>>(part, sc, sh, gam, bb, l);
    if(l < NL-1) lif_k<unsigned char><<<dim3(NBH/64), dim3(64), 0, stream>>>(out, spk, sc, sh, beta, U0, l);
    else         lif_k<float>        <<<dim3(NBH/64), dim3(64), 0, stream>>>(out, out, sc, sh, beta, U0, l);
  }
}